// Round 13
// baseline (665.254 us; speedup 1.0000x reference)
//
#include <hip/hip_runtime.h>
#include <hip/hip_bf16.h>
#include <cstddef>

typedef __attribute__((ext_vector_type(8))) short s16x8;
typedef __attribute__((ext_vector_type(4))) short s16x4;
typedef __attribute__((ext_vector_type(4))) float f32x4;

#define MFMA_BF16(a, b, c) __builtin_amdgcn_mfma_f32_16x16x32_bf16((a), (b), (c), 0, 0, 0)

__device__ __forceinline__ short f2bf(float f) {
    union { float f; unsigned u; } cv; cv.f = f;
    unsigned u = cv.u;
    unsigned r = (u + 0x7FFFu + ((u >> 16) & 1u)) >> 16;  // RNE
    return (short)r;
}
__device__ __forceinline__ float bf2f(unsigned short u) {
    union { unsigned u; float f; } cv; cv.u = ((unsigned)u) << 16; return cv.f;
}

__device__ __forceinline__ void gl16(const void* g, void* l) {
    __builtin_amdgcn_global_load_lds(
        (const __attribute__((address_space(1))) void*)g,
        (__attribute__((address_space(3))) void*)l, 16, 0, 0);
}

// ---------------------------------------------------------------------------
// 256x256 phase-split GEMM (T3+T4+T5 on faithful per-phase interleave).
// 8 waves (wr=w>>2 in {0,1}, wc=w&3), per-wave 128x64 out, acc[8][4].
// 2-deep K-tile dbuf (BK=64, 128 KB LDS, 1 block/CU by construction).
// Schedule ledger:
//   - STAGE(t+1 -> buf c^1) issued at P0 of tile t. WAR safe: buf c^1's
//     readers (tile t-1) drained own reads via lgkmcnt(0) before their P3
//     MFMA; end-of-P3 barrier orders all waves before this stage.
//   - RAW: vmcnt(0) at end of P3 (+ barrier) -> tile t+1 landed before
//     group t+1 reads. Loads have ~3 phases in flight => near-free drain.
//   - Phases serpentine (m0n0, m0n1, m1n1, m1n0): A-frags reused across
//     nn-phases, B-frags across P1->P2. 28 ds_read_b128 per K-tile.
//   - Per phase: reads; barrier; lgkmcnt(0); sched_barrier(0); setprio(1);
//     16 MFMA; setprio(0); barrier.  (rule #18 fence after lgkmcnt asm)
// MODE 6: P = exp(qs @ k^T) -> bf16 P half-batch + lpart partials.
// ---------------------------------------------------------------------------
template <int MODE>
__global__ __launch_bounds__(512, 2) void g256(
    const short* __restrict__ Ap, const short* __restrict__ Bp,
    void* __restrict__ Cp, int zbase, float* __restrict__ lpart)
{
    constexpr int NT = 16;
    constexpr int LDA = 1024, LDB = 1024;

    __shared__ short As[2][16384];   // 64 KB
    __shared__ short Bs[2][16384];   // 64 KB

    const int tid = threadIdx.x;
    const int n = blockIdx.x;
    const int z = (n & 3) + zbase;
    const int m_ = n >> 2;
    const int by = m_ & 7, bx = m_ >> 3;     // by fastest: consecutive blocks share B panel
    const int w = tid >> 6, l = tid & 63, l15 = l & 15, lhi = l >> 4;
    const int wr = w >> 2, wc = w & 3;
    const int X = (l15 & 7) << 3;
    const int lr8 = l >> 3, cb = l & 7, scb = cb ^ lr8;

    const size_t arow0 = (size_t)z * 2048 + (size_t)by * 256;
    const size_t brow0 = (size_t)z * 4096 + (size_t)bx * 256;

    const short* gA = Ap + (arow0 + w * 8 + lr8) * (size_t)LDA + scb * 8;
    const short* gB = Bp + (brow0 + w * 8 + lr8) * (size_t)LDB + scb * 8;

    f32x4 acc[8][4];
    #pragma unroll
    for (int mm = 0; mm < 8; ++mm)
        #pragma unroll
        for (int nn = 0; nn < 4; ++nn) acc[mm][nn] = (f32x4){0.f, 0.f, 0.f, 0.f};

    auto STAGE = [&](int c, int t) {
        #pragma unroll
        for (int i = 0; i < 4; ++i)
            gl16(gA + (size_t)(i * 64) * LDA + t * 64, &As[c][(i * 64 + w * 8) * 64]);
        #pragma unroll
        for (int i = 0; i < 4; ++i)
            gl16(gB + (size_t)(i * 64) * LDB + t * 64, &Bs[c][(i * 64 + w * 8) * 64]);
    };

    STAGE(0, 0);
    asm volatile("s_waitcnt vmcnt(0)" ::: "memory");
    __builtin_amdgcn_s_barrier();

    s16x8 a[4][2], b[2][2];

    for (int t = 0; t < NT; ++t) {
        const int c = t & 1;
        const short* Ab = &As[c][0];
        const short* Bb = &Bs[c][0];

        // ---- P0: (mh0, nh0) — read a(mh0) 8 + b(nh0) 4; bulk-stage t+1
        #pragma unroll
        for (int mm = 0; mm < 4; ++mm)
            #pragma unroll
            for (int kk = 0; kk < 2; ++kk)
                a[mm][kk] = *(const s16x8*)&Ab[(wr * 128 + mm * 16 + l15) * 64 + ((kk * 32 + lhi * 8) ^ X)];
        #pragma unroll
        for (int nn = 0; nn < 2; ++nn)
            #pragma unroll
            for (int kk = 0; kk < 2; ++kk)
                b[nn][kk] = *(const s16x8*)&Bb[(wc * 64 + nn * 16 + l15) * 64 + ((kk * 32 + lhi * 8) ^ X)];
        if (t + 1 < NT) STAGE(c ^ 1, t + 1);
        __builtin_amdgcn_s_barrier();
        asm volatile("s_waitcnt lgkmcnt(0)" ::: "memory");
        __builtin_amdgcn_sched_barrier(0);
        __builtin_amdgcn_s_setprio(1);
        #pragma unroll
        for (int mm = 0; mm < 4; ++mm)
            #pragma unroll
            for (int nn = 0; nn < 2; ++nn)
                #pragma unroll
                for (int kk = 0; kk < 2; ++kk)
                    acc[mm][nn] = MFMA_BF16(a[mm][kk], b[nn][kk], acc[mm][nn]);
        __builtin_amdgcn_s_setprio(0);
        __builtin_amdgcn_s_barrier();

        // ---- P1: (mh0, nh1) — read b(nh1) 4, reuse a
        #pragma unroll
        for (int nn = 0; nn < 2; ++nn)
            #pragma unroll
            for (int kk = 0; kk < 2; ++kk)
                b[nn][kk] = *(const s16x8*)&Bb[(wc * 64 + (2 + nn) * 16 + l15) * 64 + ((kk * 32 + lhi * 8) ^ X)];
        __builtin_amdgcn_s_barrier();
        asm volatile("s_waitcnt lgkmcnt(0)" ::: "memory");
        __builtin_amdgcn_sched_barrier(0);
        __builtin_amdgcn_s_setprio(1);
        #pragma unroll
        for (int mm = 0; mm < 4; ++mm)
            #pragma unroll
            for (int nn = 0; nn < 2; ++nn)
                #pragma unroll
                for (int kk = 0; kk < 2; ++kk)
                    acc[mm][2 + nn] = MFMA_BF16(a[mm][kk], b[nn][kk], acc[mm][2 + nn]);
        __builtin_amdgcn_s_setprio(0);
        __builtin_amdgcn_s_barrier();

        // ---- P2: (mh1, nh1) — read a(mh1) 8, reuse b
        #pragma unroll
        for (int mm = 0; mm < 4; ++mm)
            #pragma unroll
            for (int kk = 0; kk < 2; ++kk)
                a[mm][kk] = *(const s16x8*)&Ab[(wr * 128 + (4 + mm) * 16 + l15) * 64 + ((kk * 32 + lhi * 8) ^ X)];
        __builtin_amdgcn_s_barrier();
        asm volatile("s_waitcnt lgkmcnt(0)" ::: "memory");
        __builtin_amdgcn_sched_barrier(0);
        __builtin_amdgcn_s_setprio(1);
        #pragma unroll
        for (int mm = 0; mm < 4; ++mm)
            #pragma unroll
            for (int nn = 0; nn < 2; ++nn)
                #pragma unroll
                for (int kk = 0; kk < 2; ++kk)
                    acc[4 + mm][2 + nn] = MFMA_BF16(a[mm][kk], b[nn][kk], acc[4 + mm][2 + nn]);
        __builtin_amdgcn_s_setprio(0);
        __builtin_amdgcn_s_barrier();

        // ---- P3: (mh1, nh0) — read b(nh0) 4, reuse a; end-of-tile vmcnt(0)
        #pragma unroll
        for (int nn = 0; nn < 2; ++nn)
            #pragma unroll
            for (int kk = 0; kk < 2; ++kk)
                b[nn][kk] = *(const s16x8*)&Bb[(wc * 64 + nn * 16 + l15) * 64 + ((kk * 32 + lhi * 8) ^ X)];
        __builtin_amdgcn_s_barrier();
        asm volatile("s_waitcnt lgkmcnt(0)" ::: "memory");
        __builtin_amdgcn_sched_barrier(0);
        __builtin_amdgcn_s_setprio(1);
        #pragma unroll
        for (int mm = 0; mm < 4; ++mm)
            #pragma unroll
            for (int nn = 0; nn < 2; ++nn)
                #pragma unroll
                for (int kk = 0; kk < 2; ++kk)
                    acc[4 + mm][nn] = MFMA_BF16(a[mm][kk], b[nn][kk], acc[4 + mm][nn]);
        __builtin_amdgcn_s_setprio(0);
        asm volatile("s_waitcnt vmcnt(0)" ::: "memory");
        __builtin_amdgcn_s_barrier();
    }

    // ---- epilogue: P = exp(S) + lpart partial row-sums (MODE 6)
    #pragma unroll
    for (int mm = 0; mm < 8; ++mm) {
        #pragma unroll
        for (int j = 0; j < 4; ++j) {
            const int gr = by * 256 + wr * 128 + mm * 16 + lhi * 4 + j;
            float s = 0.f;
            #pragma unroll
            for (int nn = 0; nn < 4; ++nn) {
                const int gc = bx * 256 + wc * 64 + nn * 16 + l15;
                const float pv = __expf(acc[mm][nn][j]);
                s += pv;
                ((short*)Cp)[(size_t)(z & 3) * 8388608 + (size_t)gr * 4096 + gc] = f2bf(pv);
            }
            s += __shfl_xor(s, 1);
            s += __shfl_xor(s, 2);
            s += __shfl_xor(s, 4);
            s += __shfl_xor(s, 8);
            if (l15 == 0)
                lpart[((size_t)(z & 3) * 2048 + gr) * 64 + bx * 4 + wc] = s;
        }
    }
}

// ---------------------------------------------------------------------------
// Single-buffer 128x128 bf16 NT GEMM (round-7 proven, untouched).
// MODE 0: k; 1: vT; 2: q(+qs); 3: S A-f32 (A1); 4: O dual; 5: S gload;
// MODE 6: P=exp(S) fused (A1 alt); 7: O=P_half@vT^T/l dual.
// ---------------------------------------------------------------------------
template <int MODE>
__global__ __launch_bounds__(256, 2) void gemm_bf(
    const void* __restrict__ Ap, const short* __restrict__ Bp,
    const float* __restrict__ bias, const float* __restrict__ lvec,
    void* __restrict__ Cp, void* __restrict__ Cp2,
    int zbase, float* __restrict__ lpart)
{
    constexpr int NT  = (MODE == 4 || MODE == 7) ? 64 : 16;
    constexpr int LDA = (MODE == 4 || MODE == 7) ? 4096 : 1024;
    constexpr int LDB = (MODE == 4 || MODE == 7) ? 4096 : 1024;

    __shared__ short As[128 * 64];
    __shared__ short Bs[128 * 64];
    const int tid = threadIdx.x;

    int bx, by, z;
    if constexpr (MODE == 6 || MODE == 7) {
        const int n = blockIdx.x;
        z = (n & 3) + zbase; const int m = n >> 2; by = m % 16; bx = m / 16;
    } else if constexpr (MODE == 1 || MODE == 3 || MODE == 4 || MODE == 5) {
        const int n = blockIdx.x;
        constexpr int NBY = (MODE == 1) ? 8 : 16;
        z = n & 7; const int m = n >> 3; by = m % NBY; bx = m / NBY;
    } else { bx = blockIdx.x; by = blockIdx.y; z = blockIdx.z; }

    const int w = tid >> 6, l = tid & 63, l15 = l & 15, lhi = l >> 4;
    const int wy = w >> 1, wx = w & 1;
    const int X = (l15 & 7) << 3;
    const int lr8 = l >> 3, cb = l & 7, scb = cb ^ lr8;

    size_t arow0 = (size_t)by * 128, brow0 = (size_t)bx * 128;
    if constexpr (MODE == 3 || MODE == 4 || MODE == 5 || MODE == 6) arow0 += (size_t)z * 2048;
    if constexpr (MODE == 7) arow0 += (size_t)(z & 3) * 2048;
    if constexpr (MODE == 1 || MODE == 3 || MODE == 5 || MODE == 6) brow0 += (size_t)z * 4096;
    if constexpr (MODE == 4 || MODE == 7) brow0 += (size_t)z * 1024;

    const short* Ab = (const short*)Ap;
    const float* Af = (const float*)Ap;

    const short* gA = Ab + (arow0 + w * 32 + lr8) * (size_t)LDA + scb * 8;
    const short* gB = Bp + (brow0 + w * 32 + lr8) * (size_t)LDB + scb * 8;

    f32x4 acc[4][4];
    #pragma unroll
    for (int m = 0; m < 4; ++m)
        #pragma unroll
        for (int n = 0; n < 4; ++n) acc[m][n] = (f32x4){0.f, 0.f, 0.f, 0.f};

    const int r0b = tid >> 3, cb8 = (tid & 7) * 8;   // mode-2 A staging
    const int r0f = tid >> 4, kcs = tid & 15;        // mode-3 A staging

    for (int kt = 0; kt < NT; ++kt) {
        #pragma unroll
        for (int i = 0; i < 4; ++i)
            gl16(gB + (size_t)(i * 8) * LDB + kt * 64, &Bs[(w * 32 + i * 8) * 64]);
        if constexpr (MODE == 2) {
            #pragma unroll
            for (int p = 0; p < 4; ++p) {
                const int r = r0b + p * 32;
                const size_t g = (arow0 + r) * 2048 + kt * 64 + cb8;
                s16x8 u0 = *(const s16x8*)(Ab + g);
                s16x8 u1 = *(const s16x8*)(Ab + g + 1024);
                s16x8 o;
                #pragma unroll
                for (int j = 0; j < 8; ++j)
                    o[j] = f2bf(0.5f * (bf2f((unsigned short)u0[j]) + bf2f((unsigned short)u1[j])));
                *(s16x8*)&As[r * 64 + (cb8 ^ ((r & 7) * 8))] = o;
            }
        } else if constexpr (MODE == 3) {
            const int k0 = kt * 64 + kcs * 4;
            #pragma unroll
            for (int p = 0; p < 8; ++p) {
                const int r = r0f + p * 16;
                float4 u = *(const float4*)(Af + (arow0 + r) * 1024 + k0);
                s16x4 sa = { f2bf(u.x * 0.03125f), f2bf(u.y * 0.03125f),
                             f2bf(u.z * 0.03125f), f2bf(u.w * 0.03125f) };
                *(s16x4*)&As[r * 64 + ((kcs * 4) ^ ((r & 7) * 8))] = sa;
            }
        } else {
            #pragma unroll
            for (int i = 0; i < 4; ++i)
                gl16(gA + (size_t)(i * 8) * LDA + kt * 64, &As[(w * 32 + i * 8) * 64]);
        }
        __syncthreads();
        #pragma unroll
        for (int kk = 0; kk < 2; ++kk) {
            const int e = (kk * 32 + lhi * 8) ^ X;
            s16x8 af[4], bfr[4];
            #pragma unroll
            for (int m = 0; m < 4; ++m)
                af[m] = *(const s16x8*)&As[(wy * 64 + m * 16 + l15) * 64 + e];
            #pragma unroll
            for (int n = 0; n < 4; ++n)
                bfr[n] = *(const s16x8*)&Bs[(wx * 64 + n * 16 + l15) * 64 + e];
            #pragma unroll
            for (int m = 0; m < 4; ++m)
                #pragma unroll
                for (int n = 0; n < 4; ++n)
                    acc[m][n] = MFMA_BF16(af[m], bfr[n], acc[m][n]);
        }
        __syncthreads();
    }

    #pragma unroll
    for (int m = 0; m < 4; ++m) {
        #pragma unroll
        for (int j = 0; j < 4; ++j) {
            const int rl = wy * 64 + m * 16 + lhi * 4 + j;
            const int grow = by * 128 + rl;
            float radd = 0.f, rmul = 1.f;
            if constexpr (MODE == 1) radd = bias[grow];
            if constexpr (MODE == 4 || MODE == 7) rmul = 1.0f / lvec[(size_t)z * 2048 + grow];
            if constexpr (MODE == 6) {
                float s = 0.f;
                #pragma unroll
                for (int n = 0; n < 4; ++n) {
                    const int gcol = bx * 128 + wx * 64 + n * 16 + l15;
                    const float pv = __expf(acc[m][n][j]);
                    s += pv;
                    ((short*)Cp)[(size_t)(z & 3) * 8388608 + (size_t)grow * 4096 + gcol] = f2bf(pv);
                }
                s += __shfl_xor(s, 1);
                s += __shfl_xor(s, 2);
                s += __shfl_xor(s, 4);
                s += __shfl_xor(s, 8);
                if (l15 == 0)
                    lpart[((size_t)(z & 3) * 2048 + grow) * 64 + bx * 2 + wx] = s;
            } else {
                #pragma unroll
                for (int n = 0; n < 4; ++n) {
                    const int cl = wx * 64 + n * 16 + l15;
                    const int gcol = bx * 128 + cl;
                    float v = acc[m][n][j];
                    if constexpr (MODE == 0) {
                        ((short*)Cp)[(size_t)grow * 1024 + gcol] = f2bf(v + bias[gcol]);
                    } else if constexpr (MODE == 1) {
                        ((short*)Cp)[(size_t)z * 4194304 + (size_t)grow * 4096 + gcol] = f2bf(v + radd);
                    } else if constexpr (MODE == 2) {
                        const float qv = v + bias[gcol];
                        ((float*)Cp)[(size_t)grow * 1024 + gcol] = qv;
                        if (Cp2 != nullptr)
                            ((short*)Cp2)[(size_t)grow * 1024 + gcol] = f2bf(qv * 0.03125f);
                    } else if constexpr (MODE == 3 || MODE == 5) {
                        ((short*)Cp)[(size_t)z * 8388608 + (size_t)grow * 4096 + gcol] = f2bf(v);
                    } else {
                        const size_t o = ((size_t)z * 2048 + grow) * 1024 + gcol;
                        const float ov = v * rmul;
                        ((float*)Cp)[o] = ov;
                        ((float*)Cp2)[o] = ov;
                    }
                }
            }
        }
    }
}

// Sum 64 partials per row -> l (deterministic). 8192 rows per half.
__global__ __launch_bounds__(256, 4) void reduce_l(
    const float* __restrict__ lpart, float* __restrict__ lvec, int zbase)
{
    const int r = blockIdx.x * 256 + threadIdx.x;          // 0..8191
    const float4* p = (const float4*)(lpart + (size_t)r * 64);
    float s = 0.f;
    #pragma unroll
    for (int i = 0; i < 16; ++i) { float4 v = p[i]; s += v.x + v.y + v.z + v.w; }
    lvec[(size_t)zbase * 2048 + r] = s;
}

// ---------------------------------------------------------------------------
// Plan-B fallback: f32-input reg-staged GEMM (round-2 proven).
// ---------------------------------------------------------------------------
template <int MODE>
__global__ __launch_bounds__(256, 2) void gemm_f32(
    const float* __restrict__ Ap, const float* __restrict__ Bp,
    const float* __restrict__ bias, void* __restrict__ Cp, void* __restrict__ Cp2)
{
    constexpr int LDA = (MODE == 2) ? 2048 : 1024;
    __shared__ short As[128 * 64];
    __shared__ short Bs[128 * 64];
    const int tid = threadIdx.x;
    const int bx = blockIdx.x, by = blockIdx.y, z = blockIdx.z;
    const int w = tid >> 6, l = tid & 63, l15 = l & 15, lhi = l >> 4;
    const int wy = w >> 1, wx = w & 1;
    const int X = (l15 & 7) << 3;

    size_t arow0 = (size_t)by * 128, brow0 = (size_t)bx * 128;
    if constexpr (MODE == 1) brow0 += (size_t)z * 4096;

    f32x4 acc[4][4];
    #pragma unroll
    for (int m = 0; m < 4; ++m)
        #pragma unroll
        for (int n = 0; n < 4; ++n) acc[m][n] = (f32x4){0.f, 0.f, 0.f, 0.f};

    const int r0f = tid >> 4, kcs = tid & 15;
    float4 ra[8], ra2[8], rb[8];

    auto load_tile = [&](int kt) {
        const int k0 = kt * 64 + kcs * 4;
        #pragma unroll
        for (int p = 0; p < 8; ++p) {
            const int r = r0f + p * 16;
            if constexpr (MODE == 2) {
                const float* s0 = Ap + (arow0 + r) * (size_t)LDA + k0;
                ra[p] = *(const float4*)s0;
                ra2[p] = *(const float4*)(s0 + 1024);
            } else {
                ra[p] = *(const float4*)(Ap + (arow0 + r) * (size_t)LDA + k0);
            }
            rb[p] = *(const float4*)(Bp + (brow0 + r) * (size_t)1024 + k0);
        }
    };

    load_tile(0);
    for (int kt = 0; kt < 16; ++kt) {
        #pragma unroll
        for (int p = 0; p < 8; ++p) {
            const int r = r0f + p * 16;
            const int e = (kcs * 4) ^ ((r & 7) << 3);
            float ax, ay, az, aw;
            if constexpr (MODE == 2) {
                ax = 0.5f * (ra[p].x + ra2[p].x); ay = 0.5f * (ra[p].y + ra2[p].y);
                az = 0.5f * (ra[p].z + ra2[p].z); aw = 0.5f * (ra[p].w + ra2[p].w);
            } else {
                ax = ra[p].x; ay = ra[p].y; az = ra[p].z; aw = ra[p].w;
            }
            s16x4 sa = { f2bf(ax), f2bf(ay), f2bf(az), f2bf(aw) };
            *(s16x4*)&As[r * 64 + e] = sa;
            s16x4 sb = { f2bf(rb[p].x), f2bf(rb[p].y), f2bf(rb[p].z), f2bf(rb[p].w) };
            *(s16x4*)&Bs[r * 64 + e] = sb;
        }
        if (kt + 1 < 16) load_tile(kt + 1);
        __syncthreads();
        #pragma unroll
        for (int kk = 0; kk < 2; ++kk) {
            const int e = (kk * 32 + lhi * 8) ^ X;
            s16x8 af[4], bfr[4];
            #pragma unroll
            for (int m = 0; m < 4; ++m)
                af[m] = *(const s16x8*)&As[(wy * 64 + m * 16 + l15) * 64 + e];
            #pragma unroll
            for (int n = 0; n < 4; ++n)
                bfr[n] = *(const s16x8*)&Bs[(wx * 64 + n * 16 + l15) * 64 + e];
            #pragma unroll
            for (int m = 0; m < 4; ++m)
                #pragma unroll
                for (int n = 0; n < 4; ++n)
                    acc[m][n] = MFMA_BF16(af[m], bfr[n], acc[m][n]);
        }
        __syncthreads();
    }

    #pragma unroll
    for (int m = 0; m < 4; ++m) {
        #pragma unroll
        for (int j = 0; j < 4; ++j) {
            const int rl = wy * 64 + m * 16 + lhi * 4 + j;
            const int grow = by * 128 + rl;
            const float radd = (MODE == 1) ? bias[grow] : 0.f;
            #pragma unroll
            for (int n = 0; n < 4; ++n) {
                const int cl = wx * 64 + n * 16 + l15;
                const int gcol = bx * 128 + cl;
                float v = acc[m][n][j];
                if constexpr (MODE == 0) {
                    ((short*)Cp)[(size_t)grow * 1024 + gcol] = f2bf(v + bias[gcol]);
                } else if constexpr (MODE == 1) {
                    ((short*)Cp)[(size_t)z * 4194304 + (size_t)grow * 4096 + gcol] = f2bf(v + radd);
                } else {
                    const float q = v + bias[gcol];
                    ((float*)Cp)[(size_t)grow * 1024 + gcol] = q;
                    ((short*)Cp2)[(size_t)grow * 1024 + gcol] = f2bf(q * 0.03125f);
                }
            }
        }
    }
}

__global__ __launch_bounds__(256, 4) void convert_x(const float* __restrict__ x,
                                                    short* __restrict__ xb)
{
    const size_t i0 = ((size_t)blockIdx.x * 256 + threadIdx.x) * 8;
    float4 a = *(const float4*)(x + i0), b = *(const float4*)(x + i0 + 4);
    s16x8 o = { f2bf(a.x), f2bf(a.y), f2bf(a.z), f2bf(a.w),
                f2bf(b.x), f2bf(b.y), f2bf(b.z), f2bf(b.w) };
    *(s16x8*)(xb + i0) = o;
}

__global__ __launch_bounds__(256, 4) void convert_w(
    const float* __restrict__ Wq, const float* __restrict__ Wk,
    const float* __restrict__ Wv, short* __restrict__ Wb)
{
    const int gid = blockIdx.x * 256 + threadIdx.x;
    const int seg = gid >> 17;
    const size_t off = (size_t)(gid & 131071) * 8;
    const float* s = (seg == 0) ? Wq : ((seg == 1) ? Wk : Wv);
    float4 a = *(const float4*)(s + off), b = *(const float4*)(s + off + 4);
    s16x8 o = { f2bf(a.x), f2bf(a.y), f2bf(a.z), f2bf(a.w),
                f2bf(b.x), f2bf(b.y), f2bf(b.z), f2bf(b.w) };
    *(s16x8*)(Wb + (size_t)seg * 1048576 + off) = o;
}

__global__ __launch_bounds__(256, 4) void softmax_rows(
    const unsigned short* __restrict__ Sin, unsigned short* __restrict__ Pout,
    float* __restrict__ lvec)
{
    const int w = threadIdx.x >> 6, l = threadIdx.x & 63;
    const int row = blockIdx.x * 4 + w;
    const unsigned short* rp = Sin + (size_t)row * 4096;
    unsigned short* wp = Pout + (size_t)row * 4096;

    s16x8 v[8];
    #pragma unroll
    for (int c = 0; c < 8; ++c)
        v[c] = *(const s16x8*)(rp + (c * 64 + l) * 8);

    float mx = -1e30f;
    #pragma unroll
    for (int c = 0; c < 8; ++c)
        #pragma unroll
        for (int j = 0; j < 8; ++j)
            mx = fmaxf(mx, bf2f((unsigned short)v[c][j]));
    #pragma unroll
    for (int d = 1; d < 64; d <<= 1) mx = fmaxf(mx, __shfl_xor(mx, d));

    float sum = 0.f;
    #pragma unroll
    for (int c = 0; c < 8; ++c) {
        #pragma unroll
        for (int j = 0; j < 8; ++j) {
            const float p = __expf(bf2f((unsigned short)v[c][j]) - mx);
            sum += p;
            v[c][j] = f2bf(p);
        }
    }
    #pragma unroll
    for (int d = 1; d < 64; d <<= 1) sum += __shfl_xor(sum, d);

    #pragma unroll
    for (int c = 0; c < 8; ++c)
        *(s16x8*)(wp + (c * 64 + l) * 8) = v[c];
    if (l == 0) lvec[row] = sum;
}

__global__ __launch_bounds__(256, 4) void dup_out(
    const float4* __restrict__ O, float4* __restrict__ o1, float4* __restrict__ o2)
{
    const size_t i0 = (size_t)blockIdx.x * 256 + threadIdx.x;
    #pragma unroll
    for (int p = 0; p < 4; ++p) {
        const size_t i = i0 + (size_t)p * 1048576;
        const float4 t = O[i];
        o1[i] = t;
        o2[i] = t;
    }
}

extern "C" void kernel_launch(void* const* d_in, const int* in_sizes, int n_in,
                              void* d_out, int out_size, void* d_ws, size_t ws_size,
                              hipStream_t stream) {
    const float* x  = (const float*)d_in[0];
    const float* Wq = (const float*)d_in[1];
    const float* bq = (const float*)d_in[2];
    const float* Wk = (const float*)d_in[3];
    const float* bk = (const float*)d_in[4];
    const float* Wv = (const float*)d_in[5];
    const float* bv = (const float*)d_in[6];

    float* out   = (float*)d_out;
    float* q_out = out;                                  // [16384,1024] f32
    float* out1  = out + (size_t)16777216;
    float* out2  = out + (size_t)33554432;
    short* Smat  = (short*)out1;                         // bf16 [8,2048,4096] (A1/B)

    const unsigned long long NEED_A2 = 241434624ULL;
    const unsigned long long NEED_A1 = 207683584ULL;

    if ((unsigned long long)ws_size >= NEED_A2) {
        // ---- Plan A4: r11 pipeline, S via phase-split 256x256 g256.
        short* xb  = (short*)d_ws;                        // [32768,1024]
        short* Wb  = xb + (size_t)33554432;               // [Wqb|Wkb|Wvb]
        short* kws = Wb + (size_t)3145728;                // [32768,1024]
        short* vT  = kws + (size_t)33554432;              // [8,1024,4096]
        short* qs  = vT + (size_t)33554432;               // [16384,1024] (q/32)
        float* lws = (float*)(qs + (size_t)16777216);     // [16384]
        short* Pws   = (short*)d_ws;                      // P half [4,2048,4096]
        float* lpart = (float*)((char*)d_ws + 67108864);  // [8192*64]

        convert_x<<<dim3(16384, 1, 1), 256, 0, stream>>>(x, xb);
        convert_w<<<dim3(1536, 1, 1), 256, 0, stream>>>(Wq, Wk, Wv, Wb);
        gemm_bf<0><<<dim3(8, 256, 1), 256, 0, stream>>>(xb, Wb + 1048576, bk, nullptr, (void*)kws, nullptr, 0, nullptr);
        gemm_bf<1><<<dim3(2048, 1, 1), 256, 0, stream>>>(Wb + 2097152, xb, bv, nullptr, (void*)vT, nullptr, 0, nullptr);
        gemm_bf<2><<<dim3(8, 128, 1), 256, 0, stream>>>(xb, Wb, bq, nullptr, (void*)q_out, (void*)qs, 0, nullptr);
        for (int half = 0; half < 2; ++half) {
            const int zb = half * 4;
            g256<6><<<dim3(512, 1, 1), 512, 0, stream>>>(qs, kws, (void*)Pws, zb, lpart);
            reduce_l<<<dim3(32, 1, 1), 256, 0, stream>>>(lpart, lws, zb);
            gemm_bf<7><<<dim3(512, 1, 1), 256, 0, stream>>>(Pws, vT, nullptr, lws, (void*)out1, (void*)out2, zb, nullptr);
        }
    } else if ((unsigned long long)ws_size >= NEED_A1) {
        // ---- Plan A1: round-7 structure + softmax + P-in-ws
        short* xb  = (short*)d_ws;
        short* Wb  = xb + (size_t)33554432;
        short* kws = Wb + (size_t)3145728;
        short* vT  = kws + (size_t)33554432;
        float* lws = (float*)((char*)d_ws + 207618048ULL);
        unsigned short* Pws = (unsigned short*)d_ws;

        convert_x<<<dim3(16384, 1, 1), 256, 0, stream>>>(x, xb);
        convert_w<<<dim3(1536, 1, 1), 256, 0, stream>>>(Wq, Wk, Wv, Wb);
        gemm_bf<0><<<dim3(8, 256, 1), 256, 0, stream>>>(xb, Wb + 1048576, bk, nullptr, (void*)kws, nullptr, 0, nullptr);
        gemm_bf<1><<<dim3(2048, 1, 1), 256, 0, stream>>>(Wb + 2097152, xb, bv, nullptr, (void*)vT, nullptr, 0, nullptr);
        gemm_bf<2><<<dim3(8, 128, 1), 256, 0, stream>>>(xb, Wb, bq, nullptr, (void*)q_out, nullptr, 0, nullptr);
        gemm_bf<3><<<dim3(4096, 1, 1), 256, 0, stream>>>(q_out, kws, nullptr, nullptr, (void*)Smat, nullptr, 0, nullptr);
        softmax_rows<<<dim3(4096, 1, 1), 256, 0, stream>>>((const unsigned short*)Smat, Pws, lws);
        gemm_bf<4><<<dim3(1024, 1, 1), 256, 0, stream>>>(Pws, vT, nullptr, lws, (void*)out1, (void*)out2, 0, nullptr);
    } else {
        // ---- Plan B: round-2 proven fallback (168 MB ws)
        short* kws = (short*)d_ws;
        short* vT  = kws + (size_t)33554432;
        short* qs  = vT + (size_t)33554432;
        float* lws = (float*)((char*)d_ws + 167772160ULL);
        float* Ows = (float*)d_ws;

        gemm_f32<0><<<dim3(8, 256, 1), 256, 0, stream>>>(x, Wk, bk, (void*)kws, nullptr);
        gemm_f32<1><<<dim3(32, 8, 8), 256, 0, stream>>>(Wv, x, bv, (void*)vT, nullptr);
        gemm_f32<2><<<dim3(8, 128, 1), 256, 0, stream>>>(x, Wq, bq, (void*)q_out, (void*)qs);
        gemm_bf<5><<<dim3(4096, 1, 1), 256, 0, stream>>>(qs, kws, nullptr, nullptr, (void*)Smat, nullptr, 0, nullptr);
        softmax_rows<<<dim3(4096, 1, 1), 256, 0, stream>>>((const unsigned short*)Smat, (unsigned short*)Smat, lws);
        gemm_bf<4><<<dim3(1024, 1, 1), 256, 0, stream>>>(Smat, vT, nullptr, lws, (void*)Ows, (void*)Ows, 0, nullptr);
        dup_out<<<dim3(4096, 1, 1), 256, 0, stream>>>((const float4*)Ows, (float4*)out1, (float4*)out2);
    }
}

// Round 15
// 587.655 us; speedup vs baseline: 1.1320x; 1.1320x over previous
//
#include <hip/hip_runtime.h>
#include <hip/hip_bf16.h>
#include <cstddef>

typedef __attribute__((ext_vector_type(8))) short s16x8;
typedef __attribute__((ext_vector_type(4))) short s16x4;
typedef __attribute__((ext_vector_type(4))) float f32x4;

#define MFMA_BF16(a, b, c) __builtin_amdgcn_mfma_f32_16x16x32_bf16((a), (b), (c), 0, 0, 0)

__device__ __forceinline__ short f2bf(float f) {
    union { float f; unsigned u; } cv; cv.f = f;
    unsigned u = cv.u;
    unsigned r = (u + 0x7FFFu + ((u >> 16) & 1u)) >> 16;  // RNE
    return (short)r;
}
__device__ __forceinline__ float bf2f(unsigned short u) {
    union { unsigned u; float f; } cv; cv.u = ((unsigned)u) << 16; return cv.f;
}

__device__ __forceinline__ void gl16(const void* g, void* l) {
    __builtin_amdgcn_global_load_lds(
        (const __attribute__((address_space(1))) void*)g,
        (__attribute__((address_space(3))) void*)l, 16, 0, 0);
}

// ---------------------------------------------------------------------------
// Single-buffer 128x128 bf16 NT GEMM (round-7 proven structure).
// Swizzle: content chunk c (16B) of row r at chunk c^(r&7); gload: linear
// LDS dest + pre-swizzled global source (rule #21).
// MODE 0: k  = xb @ WkbT + bk            -> bf16 k   [32768,1024]
// MODE 1: vT = Wvb @ xbT + bv            -> bf16 vT  [8,1024,4096]
// MODE 2: q  = pairmean(xb) @ WqbT + bq  -> f32 q (+ bf16 qs if Cp2)  [A1]
// MODE 3: S  = (q*1/32) @ kT             -> bf16 S   (A f32 reg-staged, A1)
// MODE 4: O  = P @ vTT (K=4096)          -> f32 * 1/l[row] -> Cp AND Cp2
// MODE 5: S  = qs @ kT                   -> bf16 S   (pure gload, A1/B)
// MODE 6: P  = exp(qs @ kT)              -> bf16 P half-batch (z=(n&3)+zbase)
//          + lpart row-sum partials (deterministic, no atomics)
// MODE 7: O  = P_half @ vTT / l          -> dual write (z=(n&3)+zbase)
// MODE 8: q  = xpb @ WqbT + bq           -> f32 q AND bf16 qs (pure gload)
// ---------------------------------------------------------------------------
template <int MODE>
__global__ __launch_bounds__(256, 2) void gemm_bf(
    const void* __restrict__ Ap, const short* __restrict__ Bp,
    const float* __restrict__ bias, const float* __restrict__ lvec,
    void* __restrict__ Cp, void* __restrict__ Cp2,
    int zbase, float* __restrict__ lpart)
{
    constexpr int NT  = (MODE == 4 || MODE == 7) ? 64 : 16;
    constexpr int LDA = (MODE == 4 || MODE == 7) ? 4096 : 1024;
    constexpr int LDB = (MODE == 4 || MODE == 7) ? 4096 : 1024;

    __shared__ short As[128 * 64];
    __shared__ short Bs[128 * 64];
    const int tid = threadIdx.x;

    int bx, by, z;
    if constexpr (MODE == 6 || MODE == 7) {
        const int n = blockIdx.x;
        z = (n & 3) + zbase; const int m = n >> 2; by = m % 16; bx = m / 16;
    } else if constexpr (MODE == 1 || MODE == 3 || MODE == 4 || MODE == 5) {
        const int n = blockIdx.x;
        constexpr int NBY = (MODE == 1) ? 8 : 16;
        z = n & 7; const int m = n >> 3; by = m % NBY; bx = m / NBY;
    } else { bx = blockIdx.x; by = blockIdx.y; z = blockIdx.z; }

    const int w = tid >> 6, l = tid & 63, l15 = l & 15, lhi = l >> 4;
    const int wy = w >> 1, wx = w & 1;
    const int X = (l15 & 7) << 3;
    const int lr8 = l >> 3, cb = l & 7, scb = cb ^ lr8;

    size_t arow0 = (size_t)by * 128, brow0 = (size_t)bx * 128;
    if constexpr (MODE == 3 || MODE == 4 || MODE == 5 || MODE == 6) arow0 += (size_t)z * 2048;
    if constexpr (MODE == 7) arow0 += (size_t)(z & 3) * 2048;
    if constexpr (MODE == 1 || MODE == 3 || MODE == 5 || MODE == 6) brow0 += (size_t)z * 4096;
    if constexpr (MODE == 4 || MODE == 7) brow0 += (size_t)z * 1024;

    const short* Ab = (const short*)Ap;
    const float* Af = (const float*)Ap;

    const short* gA = Ab + (arow0 + w * 32 + lr8) * (size_t)LDA + scb * 8;
    const short* gB = Bp + (brow0 + w * 32 + lr8) * (size_t)LDB + scb * 8;

    f32x4 acc[4][4];
    #pragma unroll
    for (int m = 0; m < 4; ++m)
        #pragma unroll
        for (int n = 0; n < 4; ++n) acc[m][n] = (f32x4){0.f, 0.f, 0.f, 0.f};

    const int r0b = tid >> 3, cb8 = (tid & 7) * 8;   // mode-2 A staging
    const int r0f = tid >> 4, kcs = tid & 15;        // mode-3 A staging

    for (int kt = 0; kt < NT; ++kt) {
        #pragma unroll
        for (int i = 0; i < 4; ++i)
            gl16(gB + (size_t)(i * 8) * LDB + kt * 64, &Bs[(w * 32 + i * 8) * 64]);
        if constexpr (MODE == 2) {
            #pragma unroll
            for (int p = 0; p < 4; ++p) {
                const int r = r0b + p * 32;
                const size_t g = (arow0 + r) * 2048 + kt * 64 + cb8;
                s16x8 u0 = *(const s16x8*)(Ab + g);
                s16x8 u1 = *(const s16x8*)(Ab + g + 1024);
                s16x8 o;
                #pragma unroll
                for (int j = 0; j < 8; ++j)
                    o[j] = f2bf(0.5f * (bf2f((unsigned short)u0[j]) + bf2f((unsigned short)u1[j])));
                *(s16x8*)&As[r * 64 + (cb8 ^ ((r & 7) * 8))] = o;
            }
        } else if constexpr (MODE == 3) {
            const int k0 = kt * 64 + kcs * 4;
            #pragma unroll
            for (int p = 0; p < 8; ++p) {
                const int r = r0f + p * 16;
                float4 u = *(const float4*)(Af + (arow0 + r) * 1024 + k0);
                s16x4 sa = { f2bf(u.x * 0.03125f), f2bf(u.y * 0.03125f),
                             f2bf(u.z * 0.03125f), f2bf(u.w * 0.03125f) };
                *(s16x4*)&As[r * 64 + ((kcs * 4) ^ ((r & 7) * 8))] = sa;
            }
        } else {
            #pragma unroll
            for (int i = 0; i < 4; ++i)
                gl16(gA + (size_t)(i * 8) * LDA + kt * 64, &As[(w * 32 + i * 8) * 64]);
        }
        __syncthreads();
        #pragma unroll
        for (int kk = 0; kk < 2; ++kk) {
            const int e = (kk * 32 + lhi * 8) ^ X;
            s16x8 af[4], bfr[4];
            #pragma unroll
            for (int m = 0; m < 4; ++m)
                af[m] = *(const s16x8*)&As[(wy * 64 + m * 16 + l15) * 64 + e];
            #pragma unroll
            for (int n = 0; n < 4; ++n)
                bfr[n] = *(const s16x8*)&Bs[(wx * 64 + n * 16 + l15) * 64 + e];
            #pragma unroll
            for (int m = 0; m < 4; ++m)
                #pragma unroll
                for (int n = 0; n < 4; ++n)
                    acc[m][n] = MFMA_BF16(af[m], bfr[n], acc[m][n]);
        }
        __syncthreads();
    }

    #pragma unroll
    for (int m = 0; m < 4; ++m) {
        #pragma unroll
        for (int j = 0; j < 4; ++j) {
            const int rl = wy * 64 + m * 16 + lhi * 4 + j;
            const int grow = by * 128 + rl;
            float radd = 0.f, rmul = 1.f;
            if constexpr (MODE == 1) radd = bias[grow];
            if constexpr (MODE == 4 || MODE == 7) rmul = 1.0f / lvec[(size_t)z * 2048 + grow];
            if constexpr (MODE == 6) {
                // P = exp(S) bf16 (|S|max ~ 6, fp32-safe; identical P/sum
                // ratio as softmax) + deterministic row-sum partials.
                float s = 0.f;
                #pragma unroll
                for (int n = 0; n < 4; ++n) {
                    const int gcol = bx * 128 + wx * 64 + n * 16 + l15;
                    const float pv = __expf(acc[m][n][j]);
                    s += pv;
                    ((short*)Cp)[(size_t)(z & 3) * 8388608 + (size_t)grow * 4096 + gcol] = f2bf(pv);
                }
                s += __shfl_xor(s, 1);
                s += __shfl_xor(s, 2);
                s += __shfl_xor(s, 4);
                s += __shfl_xor(s, 8);
                if (l15 == 0)
                    lpart[((size_t)(z & 3) * 2048 + grow) * 64 + bx * 2 + wx] = s;
            } else {
                #pragma unroll
                for (int n = 0; n < 4; ++n) {
                    const int cl = wx * 64 + n * 16 + l15;
                    const int gcol = bx * 128 + cl;
                    float v = acc[m][n][j];
                    if constexpr (MODE == 0) {
                        ((short*)Cp)[(size_t)grow * 1024 + gcol] = f2bf(v + bias[gcol]);
                    } else if constexpr (MODE == 1) {
                        ((short*)Cp)[(size_t)z * 4194304 + (size_t)grow * 4096 + gcol] = f2bf(v + radd);
                    } else if constexpr (MODE == 2) {
                        const float qv = v + bias[gcol];
                        ((float*)Cp)[(size_t)grow * 1024 + gcol] = qv;
                        if (Cp2 != nullptr)
                            ((short*)Cp2)[(size_t)grow * 1024 + gcol] = f2bf(qv * 0.03125f);
                    } else if constexpr (MODE == 8) {
                        const float qv = v + bias[gcol];
                        ((float*)Cp)[(size_t)grow * 1024 + gcol] = qv;
                        ((short*)Cp2)[(size_t)grow * 1024 + gcol] = f2bf(qv * 0.03125f);
                    } else if constexpr (MODE == 3 || MODE == 5) {
                        ((short*)Cp)[(size_t)z * 8388608 + (size_t)grow * 4096 + gcol] = f2bf(v);
                    } else {
                        const size_t o = ((size_t)z * 2048 + grow) * 1024 + gcol;
                        const float ov = v * rmul;
                        ((float*)Cp)[o] = ov;
                        ((float*)Cp2)[o] = ov;
                    }
                }
            }
        }
    }
}

// Sum 64 partials per row -> l (deterministic). 8192 rows per half.
__global__ __launch_bounds__(256, 4) void reduce_l(
    const float* __restrict__ lpart, float* __restrict__ lvec, int zbase)
{
    const int r = blockIdx.x * 256 + threadIdx.x;          // 0..8191
    const float4* p = (const float4*)(lpart + (size_t)r * 64);
    float s = 0.f;
    #pragma unroll
    for (int i = 0; i < 16; ++i) { float4 v = p[i]; s += v.x + v.y + v.z + v.w; }
    lvec[(size_t)zbase * 2048 + r] = s;
}

// ---------------------------------------------------------------------------
// Plan-B fallback: f32-input reg-staged GEMM (round-2 proven).
// ---------------------------------------------------------------------------
template <int MODE>
__global__ __launch_bounds__(256, 2) void gemm_f32(
    const float* __restrict__ Ap, const float* __restrict__ Bp,
    const float* __restrict__ bias, void* __restrict__ Cp, void* __restrict__ Cp2)
{
    constexpr int LDA = (MODE == 2) ? 2048 : 1024;
    __shared__ short As[128 * 64];
    __shared__ short Bs[128 * 64];
    const int tid = threadIdx.x;
    const int bx = blockIdx.x, by = blockIdx.y, z = blockIdx.z;
    const int w = tid >> 6, l = tid & 63, l15 = l & 15, lhi = l >> 4;
    const int wy = w >> 1, wx = w & 1;
    const int X = (l15 & 7) << 3;

    size_t arow0 = (size_t)by * 128, brow0 = (size_t)bx * 128;
    if constexpr (MODE == 1) brow0 += (size_t)z * 4096;

    f32x4 acc[4][4];
    #pragma unroll
    for (int m = 0; m < 4; ++m)
        #pragma unroll
        for (int n = 0; n < 4; ++n) acc[m][n] = (f32x4){0.f, 0.f, 0.f, 0.f};

    const int r0f = tid >> 4, kcs = tid & 15;
    float4 ra[8], ra2[8], rb[8];

    auto load_tile = [&](int kt) {
        const int k0 = kt * 64 + kcs * 4;
        #pragma unroll
        for (int p = 0; p < 8; ++p) {
            const int r = r0f + p * 16;
            if constexpr (MODE == 2) {
                const float* s0 = Ap + (arow0 + r) * (size_t)LDA + k0;
                ra[p] = *(const float4*)s0;
                ra2[p] = *(const float4*)(s0 + 1024);
            } else {
                ra[p] = *(const float4*)(Ap + (arow0 + r) * (size_t)LDA + k0);
            }
            rb[p] = *(const float4*)(Bp + (brow0 + r) * (size_t)1024 + k0);
        }
    };

    load_tile(0);
    for (int kt = 0; kt < 16; ++kt) {
        #pragma unroll
        for (int p = 0; p < 8; ++p) {
            const int r = r0f + p * 16;
            const int e = (kcs * 4) ^ ((r & 7) << 3);
            float ax, ay, az, aw;
            if constexpr (MODE == 2) {
                ax = 0.5f * (ra[p].x + ra2[p].x); ay = 0.5f * (ra[p].y + ra2[p].y);
                az = 0.5f * (ra[p].z + ra2[p].z); aw = 0.5f * (ra[p].w + ra2[p].w);
            } else {
                ax = ra[p].x; ay = ra[p].y; az = ra[p].z; aw = ra[p].w;
            }
            s16x4 sa = { f2bf(ax), f2bf(ay), f2bf(az), f2bf(aw) };
            *(s16x4*)&As[r * 64 + e] = sa;
            s16x4 sb = { f2bf(rb[p].x), f2bf(rb[p].y), f2bf(rb[p].z), f2bf(rb[p].w) };
            *(s16x4*)&Bs[r * 64 + e] = sb;
        }
        if (kt + 1 < 16) load_tile(kt + 1);
        __syncthreads();
        #pragma unroll
        for (int kk = 0; kk < 2; ++kk) {
            const int e = (kk * 32 + lhi * 8) ^ X;
            s16x8 af[4], bfr[4];
            #pragma unroll
            for (int m = 0; m < 4; ++m)
                af[m] = *(const s16x8*)&As[(wy * 64 + m * 16 + l15) * 64 + e];
            #pragma unroll
            for (int n = 0; n < 4; ++n)
                bfr[n] = *(const s16x8*)&Bs[(wx * 64 + n * 16 + l15) * 64 + e];
            #pragma unroll
            for (int m = 0; m < 4; ++m)
                #pragma unroll
                for (int n = 0; n < 4; ++n)
                    acc[m][n] = MFMA_BF16(af[m], bfr[n], acc[m][n]);
        }
        __syncthreads();
    }

    #pragma unroll
    for (int m = 0; m < 4; ++m) {
        #pragma unroll
        for (int j = 0; j < 4; ++j) {
            const int rl = wy * 64 + m * 16 + lhi * 4 + j;
            const int grow = by * 128 + rl;
            const float radd = (MODE == 1) ? bias[grow] : 0.f;
            #pragma unroll
            for (int n = 0; n < 4; ++n) {
                const int cl = wx * 64 + n * 16 + l15;
                const int gcol = bx * 128 + cl;
                float v = acc[m][n][j];
                if constexpr (MODE == 0) {
                    ((short*)Cp)[(size_t)grow * 1024 + gcol] = f2bf(v + bias[gcol]);
                } else if constexpr (MODE == 1) {
                    ((short*)Cp)[(size_t)z * 4194304 + (size_t)grow * 4096 + gcol] = f2bf(v + radd);
                } else {
                    const float q = v + bias[gcol];
                    ((float*)Cp)[(size_t)grow * 1024 + gcol] = q;
                    ((short*)Cp2)[(size_t)grow * 1024 + gcol] = f2bf(q * 0.03125f);
                }
            }
        }
    }
}

// x -> xb (bf16) AND xpb (bf16 pair-mean). One thread: 8 cols of rows 2r,2r+1.
__global__ __launch_bounds__(256, 4) void convert_x2(
    const float* __restrict__ x, short* __restrict__ xb, short* __restrict__ xpb)
{
    const int gid = blockIdx.x * 256 + threadIdx.x;          // 0..2097151
    const int prow = gid >> 7;
    const size_t c8 = (size_t)(gid & 127) * 8;
    const float* p0 = x + (size_t)(2 * prow) * 1024 + c8;
    float4 a0 = *(const float4*)p0, b0 = *(const float4*)(p0 + 4);
    float4 a1 = *(const float4*)(p0 + 1024), b1 = *(const float4*)(p0 + 1028);
    s16x8 o0 = { f2bf(a0.x), f2bf(a0.y), f2bf(a0.z), f2bf(a0.w),
                 f2bf(b0.x), f2bf(b0.y), f2bf(b0.z), f2bf(b0.w) };
    s16x8 o1 = { f2bf(a1.x), f2bf(a1.y), f2bf(a1.z), f2bf(a1.w),
                 f2bf(b1.x), f2bf(b1.y), f2bf(b1.z), f2bf(b1.w) };
    s16x8 op = { f2bf(0.5f * (a0.x + a1.x)), f2bf(0.5f * (a0.y + a1.y)),
                 f2bf(0.5f * (a0.z + a1.z)), f2bf(0.5f * (a0.w + a1.w)),
                 f2bf(0.5f * (b0.x + b1.x)), f2bf(0.5f * (b0.y + b1.y)),
                 f2bf(0.5f * (b0.z + b1.z)), f2bf(0.5f * (b0.w + b1.w)) };
    *(s16x8*)(xb + (size_t)(2 * prow) * 1024 + c8) = o0;
    *(s16x8*)(xb + (size_t)(2 * prow + 1) * 1024 + c8) = o1;
    *(s16x8*)(xpb + (size_t)prow * 1024 + c8) = op;
}

__global__ __launch_bounds__(256, 4) void convert_x(const float* __restrict__ x,
                                                    short* __restrict__ xb)
{
    const size_t i0 = ((size_t)blockIdx.x * 256 + threadIdx.x) * 8;
    float4 a = *(const float4*)(x + i0), b = *(const float4*)(x + i0 + 4);
    s16x8 o = { f2bf(a.x), f2bf(a.y), f2bf(a.z), f2bf(a.w),
                f2bf(b.x), f2bf(b.y), f2bf(b.z), f2bf(b.w) };
    *(s16x8*)(xb + i0) = o;
}

__global__ __launch_bounds__(256, 4) void convert_w(
    const float* __restrict__ Wq, const float* __restrict__ Wk,
    const float* __restrict__ Wv, short* __restrict__ Wb)
{
    const int gid = blockIdx.x * 256 + threadIdx.x;
    const int seg = gid >> 17;
    const size_t off = (size_t)(gid & 131071) * 8;
    const float* s = (seg == 0) ? Wq : ((seg == 1) ? Wk : Wv);
    float4 a = *(const float4*)(s + off), b = *(const float4*)(s + off + 4);
    s16x8 o = { f2bf(a.x), f2bf(a.y), f2bf(a.z), f2bf(a.w),
                f2bf(b.x), f2bf(b.y), f2bf(b.z), f2bf(b.w) };
    *(s16x8*)(Wb + (size_t)seg * 1048576 + off) = o;
}

__global__ __launch_bounds__(256, 4) void softmax_rows(
    const unsigned short* __restrict__ Sin, unsigned short* __restrict__ Pout,
    float* __restrict__ lvec)
{
    const int w = threadIdx.x >> 6, l = threadIdx.x & 63;
    const int row = blockIdx.x * 4 + w;
    const unsigned short* rp = Sin + (size_t)row * 4096;
    unsigned short* wp = Pout + (size_t)row * 4096;

    s16x8 v[8];
    #pragma unroll
    for (int c = 0; c < 8; ++c)
        v[c] = *(const s16x8*)(rp + (c * 64 + l) * 8);

    float mx = -1e30f;
    #pragma unroll
    for (int c = 0; c < 8; ++c)
        #pragma unroll
        for (int j = 0; j < 8; ++j)
            mx = fmaxf(mx, bf2f((unsigned short)v[c][j]));
    #pragma unroll
    for (int d = 1; d < 64; d <<= 1) mx = fmaxf(mx, __shfl_xor(mx, d));

    float sum = 0.f;
    #pragma unroll
    for (int c = 0; c < 8; ++c) {
        #pragma unroll
        for (int j = 0; j < 8; ++j) {
            const float p = __expf(bf2f((unsigned short)v[c][j]) - mx);
            sum += p;
            v[c][j] = f2bf(p);
        }
    }
    #pragma unroll
    for (int d = 1; d < 64; d <<= 1) sum += __shfl_xor(sum, d);

    #pragma unroll
    for (int c = 0; c < 8; ++c)
        *(s16x8*)(wp + (c * 64 + l) * 8) = v[c];
    if (l == 0) lvec[row] = sum;
}

__global__ __launch_bounds__(256, 4) void dup_out(
    const float4* __restrict__ O, float4* __restrict__ o1, float4* __restrict__ o2)
{
    const size_t i0 = (size_t)blockIdx.x * 256 + threadIdx.x;
    #pragma unroll
    for (int p = 0; p < 4; ++p) {
        const size_t i = i0 + (size_t)p * 1048576;
        const float4 t = O[i];
        o1[i] = t;
        o2[i] = t;
    }
}

extern "C" void kernel_launch(void* const* d_in, const int* in_sizes, int n_in,
                              void* d_out, int out_size, void* d_ws, size_t ws_size,
                              hipStream_t stream) {
    const float* x  = (const float*)d_in[0];
    const float* Wq = (const float*)d_in[1];
    const float* bq = (const float*)d_in[2];
    const float* Wk = (const float*)d_in[3];
    const float* bk = (const float*)d_in[4];
    const float* Wv = (const float*)d_in[5];
    const float* bv = (const float*)d_in[6];

    float* out   = (float*)d_out;
    float* q_out = out;                                  // [16384,1024] f32
    float* out1  = out + (size_t)16777216;
    float* out2  = out + (size_t)33554432;
    short* Smat  = (short*)out1;                         // bf16 [8,2048,4096] (A1/B)

    const unsigned long long NEED_A2 = 241434624ULL;     // xb+Wb+k+vT+qs+l (proven)
    const unsigned long long NEED_A1 = 207683584ULL;

    if ((unsigned long long)ws_size >= NEED_A2) {
        // ---- Plan A5: r11 config + xpb-precomputed q (pure-gload mode 8).
        // xpb lives in vT's slot: q-GEMM consumes it BEFORE vT-GEMM writes.
        short* xb  = (short*)d_ws;                        // [32768,1024]
        short* Wb  = xb + (size_t)33554432;               // [Wqb|Wkb|Wvb]
        short* kws = Wb + (size_t)3145728;                // [32768,1024]
        short* vT  = kws + (size_t)33554432;              // [8,1024,4096]
        short* qs  = vT + (size_t)33554432;               // [16384,1024] (q/32)
        float* lws = (float*)(qs + (size_t)16777216);     // [16384]
        short* xpb = vT;                                  // [16384,1024] transient
        short* Pws   = (short*)d_ws;                      // P half [4,2048,4096]
        float* lpart = (float*)((char*)d_ws + 67108864);  // [8192*64]

        convert_x2<<<dim3(8192, 1, 1), 256, 0, stream>>>(x, xb, xpb);
        convert_w<<<dim3(1536, 1, 1), 256, 0, stream>>>(Wq, Wk, Wv, Wb);
        gemm_bf<8><<<dim3(8, 128, 1), 256, 0, stream>>>(xpb, Wb, bq, nullptr, (void*)q_out, (void*)qs, 0, nullptr);
        gemm_bf<0><<<dim3(8, 256, 1), 256, 0, stream>>>(xb, Wb + 1048576, bk, nullptr, (void*)kws, nullptr, 0, nullptr);
        gemm_bf<1><<<dim3(2048, 1, 1), 256, 0, stream>>>(Wb + 2097152, xb, bv, nullptr, (void*)vT, nullptr, 0, nullptr);
        for (int half = 0; half < 2; ++half) {
            const int zb = half * 4;
            gemm_bf<6><<<dim3(2048, 1, 1), 256, 0, stream>>>(qs, kws, nullptr, nullptr, (void*)Pws, nullptr, zb, lpart);
            reduce_l<<<dim3(32, 1, 1), 256, 0, stream>>>(lpart, lws, zb);
            gemm_bf<7><<<dim3(512, 1, 1), 256, 0, stream>>>(Pws, vT, nullptr, lws, (void*)out1, (void*)out2, zb, nullptr);
        }
    } else if ((unsigned long long)ws_size >= NEED_A1) {
        // ---- Plan A1: round-7 structure + softmax + P-in-ws
        short* xb  = (short*)d_ws;
        short* Wb  = xb + (size_t)33554432;
        short* kws = Wb + (size_t)3145728;
        short* vT  = kws + (size_t)33554432;
        float* lws = (float*)((char*)d_ws + 207618048ULL);
        unsigned short* Pws = (unsigned short*)d_ws;

        convert_x<<<dim3(16384, 1, 1), 256, 0, stream>>>(x, xb);
        convert_w<<<dim3(1536, 1, 1), 256, 0, stream>>>(Wq, Wk, Wv, Wb);
        gemm_bf<0><<<dim3(8, 256, 1), 256, 0, stream>>>(xb, Wb + 1048576, bk, nullptr, (void*)kws, nullptr, 0, nullptr);
        gemm_bf<1><<<dim3(2048, 1, 1), 256, 0, stream>>>(Wb + 2097152, xb, bv, nullptr, (void*)vT, nullptr, 0, nullptr);
        gemm_bf<2><<<dim3(8, 128, 1), 256, 0, stream>>>(xb, Wb, bq, nullptr, (void*)q_out, nullptr, 0, nullptr);
        gemm_bf<3><<<dim3(4096, 1, 1), 256, 0, stream>>>(q_out, kws, nullptr, nullptr, (void*)Smat, nullptr, 0, nullptr);
        softmax_rows<<<dim3(4096, 1, 1), 256, 0, stream>>>((const unsigned short*)Smat, Pws, lws);
        gemm_bf<4><<<dim3(1024, 1, 1), 256, 0, stream>>>(Pws, vT, nullptr, lws, (void*)out1, (void*)out2, 0, nullptr);
    } else {
        // ---- Plan B: round-2 proven fallback (168 MB ws)
        short* kws = (short*)d_ws;
        short* vT  = kws + (size_t)33554432;
        short* qs  = vT + (size_t)33554432;
        float* lws = (float*)((char*)d_ws + 167772160ULL);
        float* Ows = (float*)d_ws;

        gemm_f32<0><<<dim3(8, 256, 1), 256, 0, stream>>>(x, Wk, bk, (void*)kws, nullptr);
        gemm_f32<1><<<dim3(32, 8, 8), 256, 0, stream>>>(Wv, x, bv, (void*)vT, nullptr);
        gemm_f32<2><<<dim3(8, 128, 1), 256, 0, stream>>>(x, Wq, bq, (void*)q_out, (void*)qs);
        gemm_bf<5><<<dim3(4096, 1, 1), 256, 0, stream>>>(qs, kws, nullptr, nullptr, (void*)Smat, nullptr, 0, nullptr);
        softmax_rows<<<dim3(4096, 1, 1), 256, 0, stream>>>((const unsigned short*)Smat, (unsigned short*)Smat, lws);
        gemm_bf<4><<<dim3(1024, 1, 1), 256, 0, stream>>>(Smat, vT, nullptr, lws, (void*)Ows, (void*)Ows, 0, nullptr);
        dup_out<<<dim3(4096, 1, 1), 256, 0, stream>>>((const float4*)Ows, (float4*)out1, (float4*)out2);
    }
}

// Round 16
// 575.962 us; speedup vs baseline: 1.1550x; 1.0203x over previous
//
#include <hip/hip_runtime.h>
#include <hip/hip_bf16.h>
#include <cstddef>

typedef __attribute__((ext_vector_type(8))) short s16x8;
typedef __attribute__((ext_vector_type(4))) short s16x4;
typedef __attribute__((ext_vector_type(4))) float f32x4;

#define MFMA_BF16(a, b, c) __builtin_amdgcn_mfma_f32_16x16x32_bf16((a), (b), (c), 0, 0, 0)

__device__ __forceinline__ short f2bf(float f) {
    union { float f; unsigned u; } cv; cv.f = f;
    unsigned u = cv.u;
    unsigned r = (u + 0x7FFFu + ((u >> 16) & 1u)) >> 16;  // RNE
    return (short)r;
}
__device__ __forceinline__ float bf2f(unsigned short u) {
    union { unsigned u; float f; } cv; cv.u = ((unsigned)u) << 16; return cv.f;
}

__device__ __forceinline__ void gl16(const void* g, void* l) {
    __builtin_amdgcn_global_load_lds(
        (const __attribute__((address_space(1))) void*)g,
        (__attribute__((address_space(3))) void*)l, 16, 0, 0);
}

// ---------------------------------------------------------------------------
// Single-buffer 128x128 bf16 NT GEMM (round-7 proven structure).
// Swizzle: content chunk c (16B) of row r at chunk c^(r&7); gload: linear
// LDS dest + pre-swizzled global source (rule #21).
// XCD swizzle (T1, bijective since nwg%8==0): swz=(n&7)*(nwg/8)+(n>>3);
// decode by fastest, bx next, z slowest -> each XCD chunk stays in one
// batch with A/B panels L2-hot.
// MODE 0: k  = xb @ WkbT + bk            -> bf16 k   [32768,1024]  (1-D 2048)
// MODE 1: vT = Wvb @ xbT + bv            -> bf16 vT  [8,1024,4096] (1-D 2048)
// MODE 2: q  = pairmean(xb) @ WqbT + bq  -> f32 q (+ bf16 qs if Cp2)  [A1]
// MODE 3: S  = (q*1/32) @ kT             -> bf16 S   (A f32 reg-staged, A1)
// MODE 4: O  = P @ vTT (K=4096)          -> f32 * 1/l[row] -> Cp AND Cp2
// MODE 5: S  = qs @ kT                   -> bf16 S   (pure gload, A1/B)
// MODE 6: P  = exp(qs @ kT)              -> bf16 P half-batch + lpart
// MODE 7: O  = P_half @ vTT / l          -> dual write
// MODE 8: q  = xpb @ WqbT + bq           -> f32 q AND bf16 qs (pure gload)
// ---------------------------------------------------------------------------
template <int MODE>
__global__ __launch_bounds__(256, 2) void gemm_bf(
    const void* __restrict__ Ap, const short* __restrict__ Bp,
    const float* __restrict__ bias, const float* __restrict__ lvec,
    void* __restrict__ Cp, void* __restrict__ Cp2,
    int zbase, float* __restrict__ lpart)
{
    constexpr int NT  = (MODE == 4 || MODE == 7) ? 64 : 16;
    constexpr int LDA = (MODE == 4 || MODE == 7) ? 4096 : 1024;
    constexpr int LDB = (MODE == 4 || MODE == 7) ? 4096 : 1024;

    __shared__ short As[128 * 64];
    __shared__ short Bs[128 * 64];
    const int tid = threadIdx.x;

    int bx, by, z;
    if constexpr (MODE == 6) {
        const int swz = (blockIdx.x & 7) * 256 + (blockIdx.x >> 3);   // nwg=2048
        by = swz % 16; bx = (swz / 16) % 32; z = swz / 512 + zbase;
    } else if constexpr (MODE == 7) {
        const int swz = (blockIdx.x & 7) * 64 + (blockIdx.x >> 3);    // nwg=512
        by = swz % 16; bx = (swz / 16) % 8; z = swz / 128 + zbase;
    } else if constexpr (MODE == 0) {
        const int swz = (blockIdx.x & 7) * 256 + (blockIdx.x >> 3);   // nwg=2048
        bx = swz & 7; by = swz >> 3; z = 0;                           // bx fastest: A-tile reuse
    } else if constexpr (MODE == 1) {
        const int swz = (blockIdx.x & 7) * 256 + (blockIdx.x >> 3);   // nwg=2048
        by = swz % 8; bx = (swz / 8) % 32; z = swz / 256;
    } else if constexpr (MODE == 3 || MODE == 4 || MODE == 5) {
        const int n = blockIdx.x;
        z = n & 7; const int m = n >> 3; by = m % 16; bx = m / 16;
    } else { bx = blockIdx.x; by = blockIdx.y; z = blockIdx.z; }

    const int w = tid >> 6, l = tid & 63, l15 = l & 15, lhi = l >> 4;
    const int wy = w >> 1, wx = w & 1;
    const int X = (l15 & 7) << 3;
    const int lr8 = l >> 3, cb = l & 7, scb = cb ^ lr8;

    size_t arow0 = (size_t)by * 128, brow0 = (size_t)bx * 128;
    if constexpr (MODE == 3 || MODE == 4 || MODE == 5 || MODE == 6) arow0 += (size_t)z * 2048;
    if constexpr (MODE == 7) arow0 += (size_t)(z & 3) * 2048;
    if constexpr (MODE == 1 || MODE == 3 || MODE == 5 || MODE == 6) brow0 += (size_t)z * 4096;
    if constexpr (MODE == 4 || MODE == 7) brow0 += (size_t)z * 1024;

    const short* Ab = (const short*)Ap;
    const float* Af = (const float*)Ap;

    const short* gA = Ab + (arow0 + w * 32 + lr8) * (size_t)LDA + scb * 8;
    const short* gB = Bp + (brow0 + w * 32 + lr8) * (size_t)LDB + scb * 8;

    f32x4 acc[4][4];
    #pragma unroll
    for (int m = 0; m < 4; ++m)
        #pragma unroll
        for (int n = 0; n < 4; ++n) acc[m][n] = (f32x4){0.f, 0.f, 0.f, 0.f};

    const int r0b = tid >> 3, cb8 = (tid & 7) * 8;   // mode-2 A staging
    const int r0f = tid >> 4, kcs = tid & 15;        // mode-3 A staging

    for (int kt = 0; kt < NT; ++kt) {
        #pragma unroll
        for (int i = 0; i < 4; ++i)
            gl16(gB + (size_t)(i * 8) * LDB + kt * 64, &Bs[(w * 32 + i * 8) * 64]);
        if constexpr (MODE == 2) {
            #pragma unroll
            for (int p = 0; p < 4; ++p) {
                const int r = r0b + p * 32;
                const size_t g = (arow0 + r) * 2048 + kt * 64 + cb8;
                s16x8 u0 = *(const s16x8*)(Ab + g);
                s16x8 u1 = *(const s16x8*)(Ab + g + 1024);
                s16x8 o;
                #pragma unroll
                for (int j = 0; j < 8; ++j)
                    o[j] = f2bf(0.5f * (bf2f((unsigned short)u0[j]) + bf2f((unsigned short)u1[j])));
                *(s16x8*)&As[r * 64 + (cb8 ^ ((r & 7) * 8))] = o;
            }
        } else if constexpr (MODE == 3) {
            const int k0 = kt * 64 + kcs * 4;
            #pragma unroll
            for (int p = 0; p < 8; ++p) {
                const int r = r0f + p * 16;
                float4 u = *(const float4*)(Af + (arow0 + r) * 1024 + k0);
                s16x4 sa = { f2bf(u.x * 0.03125f), f2bf(u.y * 0.03125f),
                             f2bf(u.z * 0.03125f), f2bf(u.w * 0.03125f) };
                *(s16x4*)&As[r * 64 + ((kcs * 4) ^ ((r & 7) * 8))] = sa;
            }
        } else {
            #pragma unroll
            for (int i = 0; i < 4; ++i)
                gl16(gA + (size_t)(i * 8) * LDA + kt * 64, &As[(w * 32 + i * 8) * 64]);
        }
        __syncthreads();
        #pragma unroll
        for (int kk = 0; kk < 2; ++kk) {
            const int e = (kk * 32 + lhi * 8) ^ X;
            s16x8 af[4], bfr[4];
            #pragma unroll
            for (int m = 0; m < 4; ++m)
                af[m] = *(const s16x8*)&As[(wy * 64 + m * 16 + l15) * 64 + e];
            #pragma unroll
            for (int n = 0; n < 4; ++n)
                bfr[n] = *(const s16x8*)&Bs[(wx * 64 + n * 16 + l15) * 64 + e];
            #pragma unroll
            for (int m = 0; m < 4; ++m)
                #pragma unroll
                for (int n = 0; n < 4; ++n)
                    acc[m][n] = MFMA_BF16(af[m], bfr[n], acc[m][n]);
        }
        __syncthreads();
    }

    #pragma unroll
    for (int m = 0; m < 4; ++m) {
        #pragma unroll
        for (int j = 0; j < 4; ++j) {
            const int rl = wy * 64 + m * 16 + lhi * 4 + j;
            const int grow = by * 128 + rl;
            float radd = 0.f, rmul = 1.f;
            if constexpr (MODE == 1) radd = bias[grow];
            if constexpr (MODE == 4 || MODE == 7) rmul = 1.0f / lvec[(size_t)z * 2048 + grow];
            if constexpr (MODE == 6) {
                // P = exp(S) bf16 (|S|max ~ 6, fp32-safe; identical P/sum
                // ratio as softmax) + deterministic row-sum partials.
                float s = 0.f;
                #pragma unroll
                for (int n = 0; n < 4; ++n) {
                    const int gcol = bx * 128 + wx * 64 + n * 16 + l15;
                    const float pv = __expf(acc[m][n][j]);
                    s += pv;
                    ((short*)Cp)[(size_t)(z & 3) * 8388608 + (size_t)grow * 4096 + gcol] = f2bf(pv);
                }
                s += __shfl_xor(s, 1);
                s += __shfl_xor(s, 2);
                s += __shfl_xor(s, 4);
                s += __shfl_xor(s, 8);
                if (l15 == 0)
                    lpart[((size_t)(z & 3) * 2048 + grow) * 64 + bx * 2 + wx] = s;
            } else {
                #pragma unroll
                for (int n = 0; n < 4; ++n) {
                    const int cl = wx * 64 + n * 16 + l15;
                    const int gcol = bx * 128 + cl;
                    float v = acc[m][n][j];
                    if constexpr (MODE == 0) {
                        ((short*)Cp)[(size_t)grow * 1024 + gcol] = f2bf(v + bias[gcol]);
                    } else if constexpr (MODE == 1) {
                        ((short*)Cp)[(size_t)z * 4194304 + (size_t)grow * 4096 + gcol] = f2bf(v + radd);
                    } else if constexpr (MODE == 2) {
                        const float qv = v + bias[gcol];
                        ((float*)Cp)[(size_t)grow * 1024 + gcol] = qv;
                        if (Cp2 != nullptr)
                            ((short*)Cp2)[(size_t)grow * 1024 + gcol] = f2bf(qv * 0.03125f);
                    } else if constexpr (MODE == 8) {
                        const float qv = v + bias[gcol];
                        ((float*)Cp)[(size_t)grow * 1024 + gcol] = qv;
                        ((short*)Cp2)[(size_t)grow * 1024 + gcol] = f2bf(qv * 0.03125f);
                    } else if constexpr (MODE == 3 || MODE == 5) {
                        ((short*)Cp)[(size_t)z * 8388608 + (size_t)grow * 4096 + gcol] = f2bf(v);
                    } else {
                        const size_t o = ((size_t)z * 2048 + grow) * 1024 + gcol;
                        const float ov = v * rmul;
                        ((float*)Cp)[o] = ov;
                        ((float*)Cp2)[o] = ov;
                    }
                }
            }
        }
    }
}

// Sum 64 partials per row -> l (deterministic). 8192 rows per half.
__global__ __launch_bounds__(256, 4) void reduce_l(
    const float* __restrict__ lpart, float* __restrict__ lvec, int zbase)
{
    const int r = blockIdx.x * 256 + threadIdx.x;          // 0..8191
    const float4* p = (const float4*)(lpart + (size_t)r * 64);
    float s = 0.f;
    #pragma unroll
    for (int i = 0; i < 16; ++i) { float4 v = p[i]; s += v.x + v.y + v.z + v.w; }
    lvec[(size_t)zbase * 2048 + r] = s;
}

// ---------------------------------------------------------------------------
// Plan-B fallback: f32-input reg-staged GEMM (round-2 proven).
// ---------------------------------------------------------------------------
template <int MODE>
__global__ __launch_bounds__(256, 2) void gemm_f32(
    const float* __restrict__ Ap, const float* __restrict__ Bp,
    const float* __restrict__ bias, void* __restrict__ Cp, void* __restrict__ Cp2)
{
    constexpr int LDA = (MODE == 2) ? 2048 : 1024;
    __shared__ short As[128 * 64];
    __shared__ short Bs[128 * 64];
    const int tid = threadIdx.x;
    const int bx = blockIdx.x, by = blockIdx.y, z = blockIdx.z;
    const int w = tid >> 6, l = tid & 63, l15 = l & 15, lhi = l >> 4;
    const int wy = w >> 1, wx = w & 1;
    const int X = (l15 & 7) << 3;

    size_t arow0 = (size_t)by * 128, brow0 = (size_t)bx * 128;
    if constexpr (MODE == 1) brow0 += (size_t)z * 4096;

    f32x4 acc[4][4];
    #pragma unroll
    for (int m = 0; m < 4; ++m)
        #pragma unroll
        for (int n = 0; n < 4; ++n) acc[m][n] = (f32x4){0.f, 0.f, 0.f, 0.f};

    const int r0f = tid >> 4, kcs = tid & 15;
    float4 ra[8], ra2[8], rb[8];

    auto load_tile = [&](int kt) {
        const int k0 = kt * 64 + kcs * 4;
        #pragma unroll
        for (int p = 0; p < 8; ++p) {
            const int r = r0f + p * 16;
            if constexpr (MODE == 2) {
                const float* s0 = Ap + (arow0 + r) * (size_t)LDA + k0;
                ra[p] = *(const float4*)s0;
                ra2[p] = *(const float4*)(s0 + 1024);
            } else {
                ra[p] = *(const float4*)(Ap + (arow0 + r) * (size_t)LDA + k0);
            }
            rb[p] = *(const float4*)(Bp + (brow0 + r) * (size_t)1024 + k0);
        }
    };

    load_tile(0);
    for (int kt = 0; kt < 16; ++kt) {
        #pragma unroll
        for (int p = 0; p < 8; ++p) {
            const int r = r0f + p * 16;
            const int e = (kcs * 4) ^ ((r & 7) << 3);
            float ax, ay, az, aw;
            if constexpr (MODE == 2) {
                ax = 0.5f * (ra[p].x + ra2[p].x); ay = 0.5f * (ra[p].y + ra2[p].y);
                az = 0.5f * (ra[p].z + ra2[p].z); aw = 0.5f * (ra[p].w + ra2[p].w);
            } else {
                ax = ra[p].x; ay = ra[p].y; az = ra[p].z; aw = ra[p].w;
            }
            s16x4 sa = { f2bf(ax), f2bf(ay), f2bf(az), f2bf(aw) };
            *(s16x4*)&As[r * 64 + e] = sa;
            s16x4 sb = { f2bf(rb[p].x), f2bf(rb[p].y), f2bf(rb[p].z), f2bf(rb[p].w) };
            *(s16x4*)&Bs[r * 64 + e] = sb;
        }
        if (kt + 1 < 16) load_tile(kt + 1);
        __syncthreads();
        #pragma unroll
        for (int kk = 0; kk < 2; ++kk) {
            const int e = (kk * 32 + lhi * 8) ^ X;
            s16x8 af[4], bfr[4];
            #pragma unroll
            for (int m = 0; m < 4; ++m)
                af[m] = *(const s16x8*)&As[(wy * 64 + m * 16 + l15) * 64 + e];
            #pragma unroll
            for (int n = 0; n < 4; ++n)
                bfr[n] = *(const s16x8*)&Bs[(wx * 64 + n * 16 + l15) * 64 + e];
            #pragma unroll
            for (int m = 0; m < 4; ++m)
                #pragma unroll
                for (int n = 0; n < 4; ++n)
                    acc[m][n] = MFMA_BF16(af[m], bfr[n], acc[m][n]);
        }
        __syncthreads();
    }

    #pragma unroll
    for (int m = 0; m < 4; ++m) {
        #pragma unroll
        for (int j = 0; j < 4; ++j) {
            const int rl = wy * 64 + m * 16 + lhi * 4 + j;
            const int grow = by * 128 + rl;
            const float radd = (MODE == 1) ? bias[grow] : 0.f;
            #pragma unroll
            for (int n = 0; n < 4; ++n) {
                const int cl = wx * 64 + n * 16 + l15;
                const int gcol = bx * 128 + cl;
                float v = acc[m][n][j];
                if constexpr (MODE == 0) {
                    ((short*)Cp)[(size_t)grow * 1024 + gcol] = f2bf(v + bias[gcol]);
                } else if constexpr (MODE == 1) {
                    ((short*)Cp)[(size_t)z * 4194304 + (size_t)grow * 4096 + gcol] = f2bf(v + radd);
                } else {
                    const float q = v + bias[gcol];
                    ((float*)Cp)[(size_t)grow * 1024 + gcol] = q;
                    ((short*)Cp2)[(size_t)grow * 1024 + gcol] = f2bf(q * 0.03125f);
                }
            }
        }
    }
}

// x -> xb (bf16) AND xpb (bf16 pair-mean). One thread: 8 cols of rows 2r,2r+1.
__global__ __launch_bounds__(256, 4) void convert_x2(
    const float* __restrict__ x, short* __restrict__ xb, short* __restrict__ xpb)
{
    const int gid = blockIdx.x * 256 + threadIdx.x;          // 0..2097151
    const int prow = gid >> 7;
    const size_t c8 = (size_t)(gid & 127) * 8;
    const float* p0 = x + (size_t)(2 * prow) * 1024 + c8;
    float4 a0 = *(const float4*)p0, b0 = *(const float4*)(p0 + 4);
    float4 a1 = *(const float4*)(p0 + 1024), b1 = *(const float4*)(p0 + 1028);
    s16x8 o0 = { f2bf(a0.x), f2bf(a0.y), f2bf(a0.z), f2bf(a0.w),
                 f2bf(b0.x), f2bf(b0.y), f2bf(b0.z), f2bf(b0.w) };
    s16x8 o1 = { f2bf(a1.x), f2bf(a1.y), f2bf(a1.z), f2bf(a1.w),
                 f2bf(b1.x), f2bf(b1.y), f2bf(b1.z), f2bf(b1.w) };
    s16x8 op = { f2bf(0.5f * (a0.x + a1.x)), f2bf(0.5f * (a0.y + a1.y)),
                 f2bf(0.5f * (a0.z + a1.z)), f2bf(0.5f * (a0.w + a1.w)),
                 f2bf(0.5f * (b0.x + b1.x)), f2bf(0.5f * (b0.y + b1.y)),
                 f2bf(0.5f * (b0.z + b1.z)), f2bf(0.5f * (b0.w + b1.w)) };
    *(s16x8*)(xb + (size_t)(2 * prow) * 1024 + c8) = o0;
    *(s16x8*)(xb + (size_t)(2 * prow + 1) * 1024 + c8) = o1;
    *(s16x8*)(xpb + (size_t)prow * 1024 + c8) = op;
}

__global__ __launch_bounds__(256, 4) void convert_x(const float* __restrict__ x,
                                                    short* __restrict__ xb)
{
    const size_t i0 = ((size_t)blockIdx.x * 256 + threadIdx.x) * 8;
    float4 a = *(const float4*)(x + i0), b = *(const float4*)(x + i0 + 4);
    s16x8 o = { f2bf(a.x), f2bf(a.y), f2bf(a.z), f2bf(a.w),
                f2bf(b.x), f2bf(b.y), f2bf(b.z), f2bf(b.w) };
    *(s16x8*)(xb + i0) = o;
}

__global__ __launch_bounds__(256, 4) void convert_w(
    const float* __restrict__ Wq, const float* __restrict__ Wk,
    const float* __restrict__ Wv, short* __restrict__ Wb)
{
    const int gid = blockIdx.x * 256 + threadIdx.x;
    const int seg = gid >> 17;
    const size_t off = (size_t)(gid & 131071) * 8;
    const float* s = (seg == 0) ? Wq : ((seg == 1) ? Wk : Wv);
    float4 a = *(const float4*)(s + off), b = *(const float4*)(s + off + 4);
    s16x8 o = { f2bf(a.x), f2bf(a.y), f2bf(a.z), f2bf(a.w),
                f2bf(b.x), f2bf(b.y), f2bf(b.z), f2bf(b.w) };
    *(s16x8*)(Wb + (size_t)seg * 1048576 + off) = o;
}

__global__ __launch_bounds__(256, 4) void softmax_rows(
    const unsigned short* __restrict__ Sin, unsigned short* __restrict__ Pout,
    float* __restrict__ lvec)
{
    const int w = threadIdx.x >> 6, l = threadIdx.x & 63;
    const int row = blockIdx.x * 4 + w;
    const unsigned short* rp = Sin + (size_t)row * 4096;
    unsigned short* wp = Pout + (size_t)row * 4096;

    s16x8 v[8];
    #pragma unroll
    for (int c = 0; c < 8; ++c)
        v[c] = *(const s16x8*)(rp + (c * 64 + l) * 8);

    float mx = -1e30f;
    #pragma unroll
    for (int c = 0; c < 8; ++c)
        #pragma unroll
        for (int j = 0; j < 8; ++j)
            mx = fmaxf(mx, bf2f((unsigned short)v[c][j]));
    #pragma unroll
    for (int d = 1; d < 64; d <<= 1) mx = fmaxf(mx, __shfl_xor(mx, d));

    float sum = 0.f;
    #pragma unroll
    for (int c = 0; c < 8; ++c) {
        #pragma unroll
        for (int j = 0; j < 8; ++j) {
            const float p = __expf(bf2f((unsigned short)v[c][j]) - mx);
            sum += p;
            v[c][j] = f2bf(p);
        }
    }
    #pragma unroll
    for (int d = 1; d < 64; d <<= 1) sum += __shfl_xor(sum, d);

    #pragma unroll
    for (int c = 0; c < 8; ++c)
        *(s16x8*)(wp + (c * 64 + l) * 8) = v[c];
    if (l == 0) lvec[row] = sum;
}

__global__ __launch_bounds__(256, 4) void dup_out(
    const float4* __restrict__ O, float4* __restrict__ o1, float4* __restrict__ o2)
{
    const size_t i0 = (size_t)blockIdx.x * 256 + threadIdx.x;
    #pragma unroll
    for (int p = 0; p < 4; ++p) {
        const size_t i = i0 + (size_t)p * 1048576;
        const float4 t = O[i];
        o1[i] = t;
        o2[i] = t;
    }
}

extern "C" void kernel_launch(void* const* d_in, const int* in_sizes, int n_in,
                              void* d_out, int out_size, void* d_ws, size_t ws_size,
                              hipStream_t stream) {
    const float* x  = (const float*)d_in[0];
    const float* Wq = (const float*)d_in[1];
    const float* bq = (const float*)d_in[2];
    const float* Wk = (const float*)d_in[3];
    const float* bk = (const float*)d_in[4];
    const float* Wv = (const float*)d_in[5];
    const float* bv = (const float*)d_in[6];

    float* out   = (float*)d_out;
    float* q_out = out;                                  // [16384,1024] f32
    float* out1  = out + (size_t)16777216;
    float* out2  = out + (size_t)33554432;
    short* Smat  = (short*)out1;                         // bf16 [8,2048,4096] (A1/B)

    const unsigned long long NEED_A2 = 241434624ULL;     // xb+Wb+k+vT+qs+l (proven)
    const unsigned long long NEED_A1 = 207683584ULL;

    if ((unsigned long long)ws_size >= NEED_A2) {
        // ---- Plan A6: A5 + XCD-bijective swizzle on k/vT/S/PV grids.
        short* xb  = (short*)d_ws;                        // [32768,1024]
        short* Wb  = xb + (size_t)33554432;               // [Wqb|Wkb|Wvb]
        short* kws = Wb + (size_t)3145728;                // [32768,1024]
        short* vT  = kws + (size_t)33554432;              // [8,1024,4096]
        short* qs  = vT + (size_t)33554432;               // [16384,1024] (q/32)
        float* lws = (float*)(qs + (size_t)16777216);     // [16384]
        short* xpb = vT;                                  // [16384,1024] transient
        short* Pws   = (short*)d_ws;                      // P half [4,2048,4096]
        float* lpart = (float*)((char*)d_ws + 67108864);  // [8192*64]

        convert_x2<<<dim3(8192, 1, 1), 256, 0, stream>>>(x, xb, xpb);
        convert_w<<<dim3(1536, 1, 1), 256, 0, stream>>>(Wq, Wk, Wv, Wb);
        gemm_bf<8><<<dim3(8, 128, 1), 256, 0, stream>>>(xpb, Wb, bq, nullptr, (void*)q_out, (void*)qs, 0, nullptr);
        gemm_bf<0><<<dim3(2048, 1, 1), 256, 0, stream>>>(xb, Wb + 1048576, bk, nullptr, (void*)kws, nullptr, 0, nullptr);
        gemm_bf<1><<<dim3(2048, 1, 1), 256, 0, stream>>>(Wb + 2097152, xb, bv, nullptr, (void*)vT, nullptr, 0, nullptr);
        for (int half = 0; half < 2; ++half) {
            const int zb = half * 4;
            gemm_bf<6><<<dim3(2048, 1, 1), 256, 0, stream>>>(qs, kws, nullptr, nullptr, (void*)Pws, nullptr, zb, lpart);
            reduce_l<<<dim3(32, 1, 1), 256, 0, stream>>>(lpart, lws, zb);
            gemm_bf<7><<<dim3(512, 1, 1), 256, 0, stream>>>(Pws, vT, nullptr, lws, (void*)out1, (void*)out2, zb, nullptr);
        }
    } else if ((unsigned long long)ws_size >= NEED_A1) {
        // ---- Plan A1: round-7 structure + softmax + P-in-ws
        short* xb  = (short*)d_ws;
        short* Wb  = xb + (size_t)33554432;
        short* kws = Wb + (size_t)3145728;
        short* vT  = kws + (size_t)33554432;
        float* lws = (float*)((char*)d_ws + 207618048ULL);
        unsigned short* Pws = (unsigned short*)d_ws;

        convert_x<<<dim3(16384, 1, 1), 256, 0, stream>>>(x, xb);
        convert_w<<<dim3(1536, 1, 1), 256, 0, stream>>>(Wq, Wk, Wv, Wb);
        gemm_bf<0><<<dim3(2048, 1, 1), 256, 0, stream>>>(xb, Wb + 1048576, bk, nullptr, (void*)kws, nullptr, 0, nullptr);
        gemm_bf<1><<<dim3(2048, 1, 1), 256, 0, stream>>>(Wb + 2097152, xb, bv, nullptr, (void*)vT, nullptr, 0, nullptr);
        gemm_bf<2><<<dim3(8, 128, 1), 256, 0, stream>>>(xb, Wb, bq, nullptr, (void*)q_out, nullptr, 0, nullptr);
        gemm_bf<3><<<dim3(4096, 1, 1), 256, 0, stream>>>(q_out, kws, nullptr, nullptr, (void*)Smat, nullptr, 0, nullptr);
        softmax_rows<<<dim3(4096, 1, 1), 256, 0, stream>>>((const unsigned short*)Smat, Pws, lws);
        gemm_bf<4><<<dim3(1024, 1, 1), 256, 0, stream>>>(Pws, vT, nullptr, lws, (void*)out1, (void*)out2, 0, nullptr);
    } else {
        // ---- Plan B: round-2 proven fallback (168 MB ws)
        short* kws = (short*)d_ws;
        short* vT  = kws + (size_t)33554432;
        short* qs  = vT + (size_t)33554432;
        float* lws = (float*)((char*)d_ws + 167772160ULL);
        float* Ows = (float*)d_ws;

        gemm_f32<0><<<dim3(8, 256, 1), 256, 0, stream>>>(x, Wk, bk, (void*)kws, nullptr);
        gemm_f32<1><<<dim3(32, 8, 8), 256, 0, stream>>>(Wv, x, bv, (void*)vT, nullptr);
        gemm_f32<2><<<dim3(8, 128, 1), 256, 0, stream>>>(x, Wq, bq, (void*)q_out, (void*)qs);
        gemm_bf<5><<<dim3(4096, 1, 1), 256, 0, stream>>>(qs, kws, nullptr, nullptr, (void*)Smat, nullptr, 0, nullptr);
        softmax_rows<<<dim3(4096, 1, 1), 256, 0, stream>>>((const unsigned short*)Smat, (unsigned short*)Smat, lws);
        gemm_bf<4><<<dim3(1024, 1, 1), 256, 0, stream>>>(Smat, vT, nullptr, lws, (void*)Ows, (void*)Ows, 0, nullptr);
        dup_out<<<dim3(4096, 1, 1), 256, 0, stream>>>((const float4*)Ows, (float4*)out1, (float4*)out2);
    }
}